// Round 6
// baseline (381.759 us; speedup 1.0000x reference)
//
#include <hip/hip_runtime.h>

typedef float floatx4 __attribute__((ext_vector_type(4)));
typedef _Float16 halfx4 __attribute__((ext_vector_type(4)));
typedef _Float16 halfx8 __attribute__((ext_vector_type(8)));

constexpr int Bsz  = 8;
constexpr int Vsz  = 8192;
constexpr int NPTS = Bsz * Vsz;
constexpr int OUTC = 1280;

// map sizes in elements (fp16 transposed maps)
constexpr size_t N3 = (size_t)Bsz * 256 * 3136;
constexpr size_t N4 = (size_t)Bsz * 512 * 784;
constexpr size_t N5 = (size_t)Bsz * 512 * 196;

// one 32B record per (point, level): corner offsets + corner weights share a cache line
struct Desc { int4 o; float4 w; };

// prep grid partition: transpose tiles for 3 levels + descriptor blocks
constexpr int TB3 = 98 * 8 * 8;    // (3136/32) hw-tiles x (256/32) c-tiles x 8 batches
constexpr int TB4 = 25 * 16 * 8;   // ceil(784/32) x (512/32) x 8
constexpr int TB5 = 7 * 16 * 8;    // ceil(196/32) x (512/32) x 8
constexpr int DTB = NPTS / 256;    // descriptor blocks, 256 pts each
constexpr int PREP_BLOCKS = TB3 + TB4 + TB5 + DTB;

// -------- transpose body: [C, HW] f32 -> [HW, C] f16 for one 32x32 tile --------
template <int C, int HW, int NTILE_HW>
__device__ __forceinline__ void transpose_body(int id, const float* __restrict__ in,
                                               _Float16* __restrict__ out,
                                               float (*tile)[33]) {
    const int b    = id & 7;
    const int rest = id >> 3;
    const int hw0  = (rest % NTILE_HW) * 32;
    const int c0   = (rest / NTILE_HW) * 32;   // C multiple of 32
    const float* inb  = in  + (size_t)b * C * HW;
    _Float16*    outb = out + (size_t)b * C * HW;
    const int tx = threadIdx.x & 31;
    const int ty = threadIdx.x >> 5;   // 0..7
#pragma unroll
    for (int k = 0; k < 4; ++k) {
        const int c  = c0 + ty + 8 * k;
        const int hw = hw0 + tx;                       // coalesced read along HW
        tile[ty + 8 * k][tx] =
            (hw < HW) ? __builtin_nontemporal_load(inb + (size_t)c * HW + hw) : 0.0f;
    }
    __syncthreads();
#pragma unroll
    for (int k = 0; k < 4; ++k) {
        const int hw = hw0 + ty + 8 * k;
        const int c  = c0 + tx;                        // coalesced write along C
        if (hw < HW) outb[(size_t)hw * C + c] = (_Float16)tile[tx][ty + 8 * k];
    }
}

// one level's descriptor math: exact floor/ceil corner semantics of the reference
__device__ __forceinline__ void make_desc(float x, float y, float s, int W, int C,
                                          Desc& d) {
    const float sx = x * s, sy = y * s;
    const float fx1 = floorf(sx), fx2 = ceilf(sx);
    const float fy1 = floorf(sy), fy2 = ceilf(sy);
    const int xi1 = (int)fx1, xi2 = (int)fx2, yi1 = (int)fy1, yi2 = (int)fy2;
    const float wx1 = fx2 - sx, wx2 = sx - fx1;
    const float wy1 = fy2 - sy, wy2 = sy - fy1;
    d.o = make_int4((yi1 * W + xi1) * C, (yi2 * W + xi1) * C,
                    (yi1 * W + xi2) * C, (yi2 * W + xi2) * C);
    d.w = make_float4(wx1 * wy1, wx1 * wy2, wx2 * wy1, wx2 * wy2);
}

// -------- fused prep: all three transposes + per-point descriptors, ONE launch ----
__global__ __launch_bounds__(256) void prep_all(const float* __restrict__ fm3,
                                                const float* __restrict__ fm4,
                                                const float* __restrict__ fm5,
                                                const float* __restrict__ coords,
                                                _Float16* __restrict__ t3,
                                                _Float16* __restrict__ t4,
                                                _Float16* __restrict__ t5,
                                                Desc* __restrict__ desc) {  // [3][NPTS]
    __shared__ float tile[32][33];
    int id = blockIdx.x;
    if (id < TB3) {
        transpose_body<256, 3136, 98>(id, fm3, t3, tile);
    } else if (id < TB3 + TB4) {
        transpose_body<512, 784, 25>(id - TB3, fm4, t4, tile);
    } else if (id < TB3 + TB4 + TB5) {
        transpose_body<512, 196, 7>(id - TB3 - TB4, fm5, t5, tile);
    } else {
        const int pt = (id - TB3 - TB4 - TB5) * 256 + threadIdx.x;  // 0..NPTS-1
        const float x = coords[(size_t)pt * 2 + 0];
        const float y = coords[(size_t)pt * 2 + 1];
        Desc d;
        make_desc(x, y, 0.125f,   56, 256, d); desc[pt] = d;
        make_desc(x, y, 0.0625f,  28, 512, d); desc[NPTS + pt] = d;
        make_desc(x, y, 0.03125f, 14, 512, d); desc[2 * NPTS + pt] = d;
    }
}

// -------- 4-wave descriptor sampler (round-5 winner + PPB=16 + fused desc) --------
// 256 threads = 4 waves:
//   wave 0   -> t3, 4 ch/lane (64 x 4  = 256 ch), 8B gathers
//   waves 1-2-> t4, 4 ch/lane (128 x 4 = 512 ch), 8B gathers
//   wave 3   -> t5, 8 ch/lane (64 x 8  = 512 ch), 16B gathers (1KB rows: line-local)
// 8 blocks/CU = 32/32 wave slots. PPB=16 -> grid 4096 = exactly 2 co-resident
// passes of 2048 blocks; per-block setup amortized 2x vs round 5. Desc o+w now
// one 32B record in one 64B line (was two streams 3MB apart).
template <int PPB>
__global__ __launch_bounds__(256) void sample_desc4(const Desc* __restrict__ desc,
                                                    const _Float16* __restrict__ t3,
                                                    const _Float16* __restrict__ t4,
                                                    const _Float16* __restrict__ t5,
                                                    float* __restrict__ out) {
    const int blk = blockIdx.x;
    const int b   = blk & 7;               // batch == XCD slot
    const int i0  = (blk >> 3) * PPB;      // point base within batch
    const int t   = threadIdx.x;

    const _Float16* src; size_t mapsz; int lvl, lc, oc;
    if (t < 64)       { src = t3; mapsz = (size_t)256 * 3136; lvl = 0; lc = 4 * t;         oc = lc;       }
    else if (t < 192) { src = t4; mapsz = (size_t)512 * 784;  lvl = 1; lc = 4 * t - 256;   oc = 256 + lc; }
    else              { src = t5; mapsz = (size_t)512 * 196;  lvl = 2; lc = 8 * (t - 192); oc = 768 + lc; }
    const _Float16* basep = src + (size_t)b * mapsz + lc;

    const Desc* db = desc + (size_t)lvl * NPTS + (size_t)b * Vsz + i0;
    float* outb = out + ((size_t)b * Vsz + i0) * OUTC + oc;

    if (t < 192) {   // wave-uniform: narrow path (t3, t4)
#pragma unroll 4
        for (int p = 0; p < PPB; ++p) {
            const int4   o = db[p].o;      // broadcast 16B, same line as w
            const float4 w = db[p].w;      // broadcast 16B
            const halfx4 a11 = *(const halfx4*)(basep + o.x);
            const halfx4 a12 = *(const halfx4*)(basep + o.y);
            const halfx4 a21 = *(const halfx4*)(basep + o.z);
            const halfx4 a22 = *(const halfx4*)(basep + o.w);
            floatx4 r;
#pragma unroll
            for (int j = 0; j < 4; ++j) {
                r[j] = (float)a11[j] * w.x + (float)a12[j] * w.y +
                       (float)a21[j] * w.z + (float)a22[j] * w.w;
            }
            __builtin_nontemporal_store(r, (floatx4*)(outb + (size_t)p * OUTC));
        }
    } else {         // wave-uniform: wide path (t5, 8 ch/lane)
#pragma unroll 4
        for (int p = 0; p < PPB; ++p) {
            const int4   o = db[p].o;
            const float4 w = db[p].w;
            const halfx8 a11 = *(const halfx8*)(basep + o.x);
            const halfx8 a12 = *(const halfx8*)(basep + o.y);
            const halfx8 a21 = *(const halfx8*)(basep + o.z);
            const halfx8 a22 = *(const halfx8*)(basep + o.w);
            floatx4 r0, r1;
#pragma unroll
            for (int j = 0; j < 4; ++j) {
                r0[j] = (float)a11[j] * w.x + (float)a12[j] * w.y +
                        (float)a21[j] * w.z + (float)a22[j] * w.w;
                r1[j] = (float)a11[j + 4] * w.x + (float)a12[j + 4] * w.y +
                        (float)a21[j + 4] * w.z + (float)a22[j + 4] * w.w;
            }
            float* op = outb + (size_t)p * OUTC;
            __builtin_nontemporal_store(r0, (floatx4*)op);
            __builtin_nontemporal_store(r1, (floatx4*)(op + 4));
        }
    }
}

// ---------------- fallback: sample straight from [B, C, H, W] ----------------
__global__ __launch_bounds__(320) void sample_direct(const float* __restrict__ coords,
                                                     const float* __restrict__ fm3,
                                                     const float* __restrict__ fm4,
                                                     const float* __restrict__ fm5,
                                                     float* __restrict__ out) {
    const int blk = blockIdx.x;
    const int b = blk & 7;
    const int v = blk >> 3;
    const float x = coords[(size_t)(b * Vsz + v) * 2 + 0];
    const float y = coords[(size_t)(b * Vsz + v) * 2 + 1];

    const int t = threadIdx.x;
    const float* src; int C, W, HW, lc; float sx, sy;
    if (t < 64) {
        src = fm3; C = 256; W = 56; HW = 3136; lc = 4 * t;       sx = x * 0.125f;   sy = y * 0.125f;
    } else if (t < 192) {
        src = fm4; C = 512; W = 28; HW = 784;  lc = 4 * t - 256; sx = x * 0.0625f;  sy = y * 0.0625f;
    } else {
        src = fm5; C = 512; W = 14; HW = 196;  lc = 4 * t - 768; sx = x * 0.03125f; sy = y * 0.03125f;
    }
    const float fx1 = floorf(sx), fx2 = ceilf(sx);
    const float fy1 = floorf(sy), fy2 = ceilf(sy);
    const int xi1 = (int)fx1, xi2 = (int)fx2, yi1 = (int)fy1, yi2 = (int)fy2;
    const float wx1 = fx2 - sx, wx2 = sx - fx1;
    const float wy1 = fy2 - sy, wy2 = sy - fy1;
    const float w11 = wx1 * wy1, w12 = wx1 * wy2, w21 = wx2 * wy1, w22 = wx2 * wy2;

    const float* baseb = src + (size_t)b * C * HW;
    const int o11 = yi1 * W + xi1, o12 = yi2 * W + xi1, o21 = yi1 * W + xi2, o22 = yi2 * W + xi2;
    float4 r;
    float* rp = (float*)&r;
#pragma unroll
    for (int j = 0; j < 4; ++j) {
        const float* pc = baseb + (size_t)(lc + j) * HW;
        rp[j] = pc[o11] * w11 + pc[o12] * w12 + pc[o21] * w21 + pc[o22] * w22;
    }
    *(float4*)(out + (size_t)(b * Vsz + v) * OUTC + 4 * t) = r;
}

extern "C" void kernel_launch(void* const* d_in, const int* in_sizes, int n_in,
                              void* d_out, int out_size, void* d_ws, size_t ws_size,
                              hipStream_t stream) {
    const float* c   = (const float*)d_in[0];
    const float* fm3 = (const float*)d_in[1];
    const float* fm4 = (const float*)d_in[2];
    const float* fm5 = (const float*)d_in[3];
    float* out = (float*)d_out;

    const size_t map_bytes  = (N3 + N4 + N5) * sizeof(_Float16);   // ~20.9 MB, %32==0
    const size_t desc_bytes = (size_t)3 * NPTS * sizeof(Desc);     // 6 MB
    const size_t need = map_bytes + desc_bytes;

    if (ws_size >= need) {
        _Float16* t3 = (_Float16*)d_ws;
        _Float16* t4 = t3 + N3;
        _Float16* t5 = t4 + N4;
        Desc* desc = (Desc*)((char*)d_ws + map_bytes);

        prep_all<<<PREP_BLOCKS, 256, 0, stream>>>(fm3, fm4, fm5, c, t3, t4, t5, desc);
        sample_desc4<16><<<Bsz * (Vsz / 16), 256, 0, stream>>>(desc, t3, t4, t5, out);
    } else {
        sample_direct<<<Bsz * Vsz, 320, 0, stream>>>(c, fm3, fm4, fm5, out);
    }
}

// Round 7
// 371.309 us; speedup vs baseline: 1.0281x; 1.0281x over previous
//
#include <hip/hip_runtime.h>

typedef float floatx4 __attribute__((ext_vector_type(4)));
typedef _Float16 halfx4 __attribute__((ext_vector_type(4)));
typedef _Float16 halfx8 __attribute__((ext_vector_type(8)));

constexpr int Bsz  = 8;
constexpr int Vsz  = 8192;
constexpr int NPTS = Bsz * Vsz;
constexpr int OUTC = 1280;

// map sizes in elements (fp16 transposed maps)
constexpr size_t N3 = (size_t)Bsz * 256 * 3136;
constexpr size_t N4 = (size_t)Bsz * 512 * 784;
constexpr size_t N5 = (size_t)Bsz * 512 * 196;

// prep grid partition: transpose tiles for 3 levels + descriptor blocks
constexpr int TB3 = 98 * 8 * 8;    // (3136/32) hw-tiles x (256/32) c-tiles x 8 batches
constexpr int TB4 = 25 * 16 * 8;   // ceil(784/32) x (512/32) x 8
constexpr int TB5 = 7 * 16 * 8;    // ceil(196/32) x (512/32) x 8
constexpr int DTB = NPTS / 256;    // descriptor blocks, 256 pts each
constexpr int PREP_BLOCKS = TB3 + TB4 + TB5 + DTB;

// -------- transpose body: [C, HW] f32 -> [HW, C] f16 for one 32x32 tile --------
template <int C, int HW, int NTILE_HW>
__device__ __forceinline__ void transpose_body(int id, const float* __restrict__ in,
                                               _Float16* __restrict__ out,
                                               float (*tile)[33]) {
    const int b    = id & 7;
    const int rest = id >> 3;
    const int hw0  = (rest % NTILE_HW) * 32;
    const int c0   = (rest / NTILE_HW) * 32;   // C multiple of 32
    const float* inb  = in  + (size_t)b * C * HW;
    _Float16*    outb = out + (size_t)b * C * HW;
    const int tx = threadIdx.x & 31;
    const int ty = threadIdx.x >> 5;   // 0..7
#pragma unroll
    for (int k = 0; k < 4; ++k) {
        const int c  = c0 + ty + 8 * k;
        const int hw = hw0 + tx;                       // coalesced read along HW
        tile[ty + 8 * k][tx] =
            (hw < HW) ? __builtin_nontemporal_load(inb + (size_t)c * HW + hw) : 0.0f;
    }
    __syncthreads();
#pragma unroll
    for (int k = 0; k < 4; ++k) {
        const int hw = hw0 + ty + 8 * k;
        const int c  = c0 + tx;                        // coalesced write along C
        if (hw < HW) outb[(size_t)hw * C + c] = (_Float16)tile[tx][ty + 8 * k];
    }
}

// one level's descriptor math: exact floor/ceil corner semantics of the reference
__device__ __forceinline__ void make_desc(float x, float y, float s, int W, int C,
                                          int4& o, float4& w) {
    const float sx = x * s, sy = y * s;
    const float fx1 = floorf(sx), fx2 = ceilf(sx);
    const float fy1 = floorf(sy), fy2 = ceilf(sy);
    const int xi1 = (int)fx1, xi2 = (int)fx2, yi1 = (int)fy1, yi2 = (int)fy2;
    const float wx1 = fx2 - sx, wx2 = sx - fx1;
    const float wy1 = fy2 - sy, wy2 = sy - fy1;
    o = make_int4((yi1 * W + xi1) * C, (yi2 * W + xi1) * C,
                  (yi1 * W + xi2) * C, (yi2 * W + xi2) * C);
    w = make_float4(wx1 * wy1, wx1 * wy2, wx2 * wy1, wx2 * wy2);
}

// -------- fused prep: all three transposes + per-point descriptors, ONE launch ----
__global__ __launch_bounds__(256) void prep_all(const float* __restrict__ fm3,
                                                const float* __restrict__ fm4,
                                                const float* __restrict__ fm5,
                                                const float* __restrict__ coords,
                                                _Float16* __restrict__ t3,
                                                _Float16* __restrict__ t4,
                                                _Float16* __restrict__ t5,
                                                int4*  __restrict__ offs,   // [3][NPTS]
                                                float4* __restrict__ wts) { // [3][NPTS]
    __shared__ float tile[32][33];
    int id = blockIdx.x;
    if (id < TB3) {
        transpose_body<256, 3136, 98>(id, fm3, t3, tile);
    } else if (id < TB3 + TB4) {
        transpose_body<512, 784, 25>(id - TB3, fm4, t4, tile);
    } else if (id < TB3 + TB4 + TB5) {
        transpose_body<512, 196, 7>(id - TB3 - TB4, fm5, t5, tile);
    } else {
        const int pt = (id - TB3 - TB4 - TB5) * 256 + threadIdx.x;  // 0..NPTS-1
        const float x = coords[(size_t)pt * 2 + 0];
        const float y = coords[(size_t)pt * 2 + 1];
        int4 o; float4 w;
        make_desc(x, y, 0.125f,   56, 256, o, w); offs[pt] = o;            wts[pt] = w;
        make_desc(x, y, 0.0625f,  28, 512, o, w); offs[NPTS + pt] = o;     wts[NPTS + pt] = w;
        make_desc(x, y, 0.03125f, 14, 512, o, w); offs[2 * NPTS + pt] = o; wts[2 * NPTS + pt] = w;
    }
}

// -------- 4-wave descriptor sampler: full-occupancy layout (round-5 winner) --------
// 256 threads = 4 waves, 8 points per block:
//   wave 0  -> t3, 4 ch/lane (64 x 4  = 256 ch), 8B gathers
//   waves 1-2 -> t4, 4 ch/lane (128 x 4 = 512 ch), 8B gathers
//   wave 3  -> t5, 8 ch/lane (64 x 8  = 512 ch), 16B gathers (1KB rows: line-local)
// 8 blocks/CU = 32/32 wave slots (vs 30/32 for the 320-thread layout).
// Inner loop: 2 broadcast desc loads, 4 gathers, FMA, NT stores (5120B
// contiguous per point across the block).
template <int PPB>
__global__ __launch_bounds__(256) void sample_desc4(const int4* __restrict__ offs,
                                                    const float4* __restrict__ wts,
                                                    const _Float16* __restrict__ t3,
                                                    const _Float16* __restrict__ t4,
                                                    const _Float16* __restrict__ t5,
                                                    float* __restrict__ out) {
    const int blk = blockIdx.x;
    const int b   = blk & 7;               // batch == XCD slot
    const int i0  = (blk >> 3) * PPB;      // point base within batch
    const int t   = threadIdx.x;

    const _Float16* src; size_t mapsz; int lvl, lc, oc;
    if (t < 64)       { src = t3; mapsz = (size_t)256 * 3136; lvl = 0; lc = 4 * t;           oc = lc;        }
    else if (t < 192) { src = t4; mapsz = (size_t)512 * 784;  lvl = 1; lc = 4 * t - 256;     oc = 256 + lc;  }
    else              { src = t5; mapsz = (size_t)512 * 196;  lvl = 2; lc = 8 * (t - 192);   oc = 768 + lc;  }
    const _Float16* basep = src + (size_t)b * mapsz + lc;

    const size_t pbase = (size_t)lvl * NPTS + (size_t)b * Vsz + i0;
    const int4*   ob = offs + pbase;
    const float4* wb = wts + pbase;
    float* outb = out + ((size_t)b * Vsz + i0) * OUTC + oc;

    if (t < 192) {   // wave-uniform: narrow path (t3, t4)
#pragma unroll 4
        for (int p = 0; p < PPB; ++p) {
            const int4   o = ob[p];        // broadcast 16B
            const float4 w = wb[p];        // broadcast 16B
            const halfx4 a11 = *(const halfx4*)(basep + o.x);
            const halfx4 a12 = *(const halfx4*)(basep + o.y);
            const halfx4 a21 = *(const halfx4*)(basep + o.z);
            const halfx4 a22 = *(const halfx4*)(basep + o.w);
            floatx4 r;
#pragma unroll
            for (int j = 0; j < 4; ++j) {
                r[j] = (float)a11[j] * w.x + (float)a12[j] * w.y +
                       (float)a21[j] * w.z + (float)a22[j] * w.w;
            }
            __builtin_nontemporal_store(r, (floatx4*)(outb + (size_t)p * OUTC));
        }
    } else {         // wave-uniform: wide path (t5, 8 ch/lane)
#pragma unroll 4
        for (int p = 0; p < PPB; ++p) {
            const int4   o = ob[p];
            const float4 w = wb[p];
            const halfx8 a11 = *(const halfx8*)(basep + o.x);
            const halfx8 a12 = *(const halfx8*)(basep + o.y);
            const halfx8 a21 = *(const halfx8*)(basep + o.z);
            const halfx8 a22 = *(const halfx8*)(basep + o.w);
            floatx4 r0, r1;
#pragma unroll
            for (int j = 0; j < 4; ++j) {
                r0[j] = (float)a11[j] * w.x + (float)a12[j] * w.y +
                        (float)a21[j] * w.z + (float)a22[j] * w.w;
                r1[j] = (float)a11[j + 4] * w.x + (float)a12[j + 4] * w.y +
                        (float)a21[j + 4] * w.z + (float)a22[j + 4] * w.w;
            }
            float* op = outb + (size_t)p * OUTC;
            __builtin_nontemporal_store(r0, (floatx4*)op);
            __builtin_nontemporal_store(r1, (floatx4*)(op + 4));
        }
    }
}

// ---------------- fallback: sample straight from [B, C, H, W] ----------------
__global__ __launch_bounds__(320) void sample_direct(const float* __restrict__ coords,
                                                     const float* __restrict__ fm3,
                                                     const float* __restrict__ fm4,
                                                     const float* __restrict__ fm5,
                                                     float* __restrict__ out) {
    const int blk = blockIdx.x;
    const int b = blk & 7;
    const int v = blk >> 3;
    const float x = coords[(size_t)(b * Vsz + v) * 2 + 0];
    const float y = coords[(size_t)(b * Vsz + v) * 2 + 1];

    const int t = threadIdx.x;
    const float* src; int C, W, HW, lc; float sx, sy;
    if (t < 64) {
        src = fm3; C = 256; W = 56; HW = 3136; lc = 4 * t;       sx = x * 0.125f;   sy = y * 0.125f;
    } else if (t < 192) {
        src = fm4; C = 512; W = 28; HW = 784;  lc = 4 * t - 256; sx = x * 0.0625f;  sy = y * 0.0625f;
    } else {
        src = fm5; C = 512; W = 14; HW = 196;  lc = 4 * t - 768; sx = x * 0.03125f; sy = y * 0.03125f;
    }
    const float fx1 = floorf(sx), fx2 = ceilf(sx);
    const float fy1 = floorf(sy), fy2 = ceilf(sy);
    const int xi1 = (int)fx1, xi2 = (int)fx2, yi1 = (int)fy1, yi2 = (int)fy2;
    const float wx1 = fx2 - sx, wx2 = sx - fx1;
    const float wy1 = fy2 - sy, wy2 = sy - fy1;
    const float w11 = wx1 * wy1, w12 = wx1 * wy2, w21 = wx2 * wy1, w22 = wx2 * wy2;

    const float* baseb = src + (size_t)b * C * HW;
    const int o11 = yi1 * W + xi1, o12 = yi2 * W + xi1, o21 = yi1 * W + xi2, o22 = yi2 * W + xi2;
    float4 r;
    float* rp = (float*)&r;
#pragma unroll
    for (int j = 0; j < 4; ++j) {
        const float* pc = baseb + (size_t)(lc + j) * HW;
        rp[j] = pc[o11] * w11 + pc[o12] * w12 + pc[o21] * w21 + pc[o22] * w22;
    }
    *(float4*)(out + (size_t)(b * Vsz + v) * OUTC + 4 * t) = r;
}

extern "C" void kernel_launch(void* const* d_in, const int* in_sizes, int n_in,
                              void* d_out, int out_size, void* d_ws, size_t ws_size,
                              hipStream_t stream) {
    const float* c   = (const float*)d_in[0];
    const float* fm3 = (const float*)d_in[1];
    const float* fm4 = (const float*)d_in[2];
    const float* fm5 = (const float*)d_in[3];
    float* out = (float*)d_out;

    const size_t map_bytes  = (N3 + N4 + N5) * sizeof(_Float16);   // ~20.9 MB, %16==0
    const size_t offs_bytes = (size_t)3 * NPTS * sizeof(int4);     // 3 MB
    const size_t wts_bytes  = (size_t)3 * NPTS * sizeof(float4);   // 3 MB
    const size_t need = map_bytes + offs_bytes + wts_bytes;

    if (ws_size >= need) {
        _Float16* t3 = (_Float16*)d_ws;
        _Float16* t4 = t3 + N3;
        _Float16* t5 = t4 + N4;
        int4*   offs = (int4*)((char*)d_ws + map_bytes);
        float4* wts  = (float4*)((char*)d_ws + map_bytes + offs_bytes);

        prep_all<<<PREP_BLOCKS, 256, 0, stream>>>(fm3, fm4, fm5, c, t3, t4, t5, offs, wts);
        sample_desc4<8><<<Bsz * (Vsz / 8), 256, 0, stream>>>(offs, wts, t3, t4, t5, out);
    } else {
        sample_direct<<<Bsz * Vsz, 320, 0, stream>>>(c, fm3, fm4, fm5, out);
    }
}